// Round 5
// baseline (363.755 us; speedup 1.0000x reference)
//
#include <hip/hip_runtime.h>

typedef __attribute__((ext_vector_type(4))) float f32x4;
typedef __attribute__((ext_vector_type(8))) short bf16x8;
typedef __attribute__((ext_vector_type(4))) short bf16x4;
typedef long fp8x8;   // 8 packed e4m3 bytes (i64 MFMA operand)

#define NH 4

// round-to-nearest-even f32 -> bf16
static __device__ __forceinline__ unsigned short f2bf(float f){
  unsigned u = __float_as_uint(f);
  u += 0x7FFFu + ((u >> 16) & 1u);
  return (unsigned short)(u >> 16);
}

// pack two f32 -> two bf16 (round-half-up) in one uint (low = a)
static __device__ __forceinline__ unsigned pack2bf(float a, float b){
  return __builtin_amdgcn_perm(__float_as_uint(b) + 0x8000u,
                               __float_as_uint(a) + 0x8000u, 0x07060302u);
}

// pack two f32 -> two bf16 TRUNCATING (1 v_perm). Used only for P: the same
// truncated P feeds both O=P*V and l=P*1, so the truncation bias cancels.
static __device__ __forceinline__ unsigned pack2bf_t(float a, float b){
  return __builtin_amdgcn_perm(__float_as_uint(b), __float_as_uint(a), 0x07060302u);
}

// pack 4 floats into 4 fp8(e4m3) bytes of one int (byte0 = a)
static __device__ __forceinline__ int pack_fp8x4(float a, float b, float c, float d){
  int w = __builtin_amdgcn_cvt_pk_fp8_f32(a, b, 0, false);
  w     = __builtin_amdgcn_cvt_pk_fp8_f32(c, d, w, true);
  return w;
}

// ---------------- weight-prep kernel (runs once per launch, 4 blocks) ------
// Per head: builds bf16 MFMA fragment-order W in ws + scaled biases.
// WF[h][s][lane][8bf16]:
//   s 0..7  = Wq^T A-frags (s=et*2+ks, pre-scaled S1):
//             lane(quad,l16) = Wq[ks*32+quad*8+j][et*16+l16], j=0..7
//   s 8..15 = Wk^T A-frags (s-8=ft*2+ks, pre-scaled S1): same mapping
//   s 16,17 = Wv B-frags: lane(quad,l16) = Wv[ks*32+quad*8+j][l16]
// bias_s[h][0..63]=bq*S1, [64..127]=bk*S1.
__global__ __launch_bounds__(256) void wprep_kernel(
    const float* __restrict__ Wq, const float* __restrict__ bq,
    const float* __restrict__ Wk, const float* __restrict__ bk,
    const float* __restrict__ Wv,
    unsigned short* __restrict__ WF, float* __restrict__ bias_s, int n)
{
  __shared__ unsigned short wqT[64*72];  // [e][f], stride 72 (16B-aligned rows)
  __shared__ unsigned short wkT[64*72];
  __shared__ unsigned short wvT[16*72];  // [d][f]

  const int t = threadIdx.x;     // 0..255
  const int h = blockIdx.x;
  const float S1 = 0.4246609001f; // sqrt((1/sqrt(64)) * log2(e))
  const int f = t >> 2, eg = t & 3;

  {
    const float4* g = (const float4*)(Wq + h*4096 + f*64 + eg*16);
    #pragma unroll
    for (int p = 0; p < 4; ++p){
      float4 d = g[p];
      int e0 = eg*16 + p*4;
      wqT[(e0+0)*72 + f] = f2bf(d.x * S1);
      wqT[(e0+1)*72 + f] = f2bf(d.y * S1);
      wqT[(e0+2)*72 + f] = f2bf(d.z * S1);
      wqT[(e0+3)*72 + f] = f2bf(d.w * S1);
    }
  }
  {
    const float4* g = (const float4*)(Wk + h*4096 + f*64 + eg*16);
    #pragma unroll
    for (int p = 0; p < 4; ++p){
      float4 d = g[p];
      int e0 = eg*16 + p*4;
      wkT[(e0+0)*72 + f] = f2bf(d.x * S1);
      wkT[(e0+1)*72 + f] = f2bf(d.y * S1);
      wkT[(e0+2)*72 + f] = f2bf(d.z * S1);
      wkT[(e0+3)*72 + f] = f2bf(d.w * S1);
    }
  }
  {
    float4 d = *(const float4*)(Wv + h*1024 + f*16 + eg*4);
    int d0 = eg*4;
    wvT[(d0+0)*72 + f] = f2bf(d.x);
    wvT[(d0+1)*72 + f] = f2bf(d.y);
    wvT[(d0+2)*72 + f] = f2bf(d.z);
    wvT[(d0+3)*72 + f] = f2bf(d.w);
  }
  if (t < 64)       bias_s[h*128 + t] = bq[h*64 + t] * S1;
  else if (t < 128) bias_s[h*128 + t] = bk[h*64 + (t-64)] * S1;
  __syncthreads();

  const int lane = t & 63, w = t >> 6;
  const int quad = lane >> 4, l16 = lane & 15;
  for (int s = w; s < 18; s += 4){
    const unsigned short* src;
    if (s < 8){      int et = s>>1,     ks = s&1;     src = wqT + (et*16+l16)*72 + ks*32 + quad*8; }
    else if (s < 16){int ft = (s-8)>>1, ks = (s-8)&1; src = wkT + (ft*16+l16)*72 + ks*32 + quad*8; }
    else {           int ks = s-16;                   src = wvT + l16*72 + ks*32 + quad*8; }
    uint4 v = *(const uint4*)src;
    *(uint4*)(WF + ((size_t)(h*18 + s)*64 + lane)*8) = v;
  }
}

// ---------------- projection kernel (MFMA) ----------------
// grid (n/64, NH), block 256 = 4 waves. Per wave: Q^T (e-tile w, 4 row-tiles),
// K^T (f-tile w, 4 key-tiles), V (row-tile w). Epilogue writes Qfr/Kt/Vt in
// fragment-tile order so ALL attn hot/prologue loads are dense.
// Vt is written CHUNK-interleaved (chunk C = pair of 16-key tiles):
// lane frag of tile T lands at (C*64+lane)*16B + (T&1)*8B, so attn's K=32 PV
// B-operand (32-key V frag) is ONE dense 16B load per lane.
__global__ __launch_bounds__(256) void proj_kernel(
    const float* __restrict__ x, const float* __restrict__ bv,
    const unsigned short* __restrict__ WF, const float* __restrict__ bias_s,
    unsigned char* __restrict__ Qfr, unsigned char* __restrict__ Kt,
    unsigned short* __restrict__ Vt, int n)
{
  __shared__ unsigned short xf[8*64*8];  // x frags: [it*2+ks][lane][8bf16]
  __shared__ float bql[64], bkl[64], bvl[16];

  const int t  = threadIdx.x;
  const int h  = blockIdx.y;
  const int r0 = blockIdx.x * 64;

  // stage x tile -> bf16 fragment order
  {
    const int r = t >> 2, cg4 = t & 3;
    const float4* g = (const float4*)(x + (size_t)(r0 + r)*64 + cg4*16);
    float4 a = g[0], b = g[1], c = g[2], d = g[3];
    unsigned u0 = pack2bf(a.x,a.y), u1 = pack2bf(a.z,a.w);
    unsigned u2 = pack2bf(b.x,b.y), u3 = pack2bf(b.z,b.w);
    unsigned u4 = pack2bf(c.x,c.y), u5 = pack2bf(c.z,c.w);
    unsigned u6 = pack2bf(d.x,d.y), u7 = pack2bf(d.z,d.w);
    const int it = r >> 4, l16r = r & 15, ks = cg4 >> 1, q0 = (cg4 & 1)*2;
    uint4* dst0 = (uint4*)(xf + ((it*2+ks)*64 + q0*16     + l16r)*8);
    uint4* dst1 = (uint4*)(xf + ((it*2+ks)*64 + (q0+1)*16 + l16r)*8);
    *dst0 = make_uint4(u0,u1,u2,u3);
    *dst1 = make_uint4(u4,u5,u6,u7);
  }
  if (t < 64)        bql[t]     = bias_s[h*128 + t];
  else if (t < 128)  bkl[t-64]  = bias_s[h*128 + t];
  else if (t < 144)  bvl[t-128] = bv[h*16 + (t-128)];
  __syncthreads();

  const int lane = t & 63, w = t >> 6;
  const int quad = lane >> 4, l16 = lane & 15;

  bf16x8 xa[8];
  #pragma unroll
  for (int i = 0; i < 8; ++i)
    xa[i] = *(const bf16x8*)(xf + (i*64 + lane)*8);

  const unsigned short* WFh = WF + (size_t)h*18*64*8;
  bf16x8 wq0 = *(const bf16x8*)(WFh + ((size_t)(     w*2 + 0)*64 + lane)*8);
  bf16x8 wq1 = *(const bf16x8*)(WFh + ((size_t)(     w*2 + 1)*64 + lane)*8);
  bf16x8 wk0 = *(const bf16x8*)(WFh + ((size_t)(8  + w*2 + 0)*64 + lane)*8);
  bf16x8 wk1 = *(const bf16x8*)(WFh + ((size_t)(8  + w*2 + 1)*64 + lane)*8);
  bf16x8 wv0 = *(const bf16x8*)(WFh + ((size_t)16*64 + lane)*8);
  bf16x8 wv1 = *(const bf16x8*)(WFh + ((size_t)17*64 + lane)*8);

  const f32x4 z = {0.f,0.f,0.f,0.f};
  f32x4 accQ[4] = {z,z,z,z};   // Q^T: rows e (tile w), cols Q-row (tile it)
  f32x4 accK[4] = {z,z,z,z};   // K^T: rows f (tile w), cols key (tile tt)
  f32x4 accV = z;

  #pragma unroll
  for (int it = 0; it < 4; ++it){
    accQ[it] = __builtin_amdgcn_mfma_f32_16x16x32_bf16(wq0, xa[it*2+0], accQ[it], 0,0,0);
    accQ[it] = __builtin_amdgcn_mfma_f32_16x16x32_bf16(wq1, xa[it*2+1], accQ[it], 0,0,0);
  }
  #pragma unroll
  for (int tt = 0; tt < 4; ++tt){
    accK[tt] = __builtin_amdgcn_mfma_f32_16x16x32_bf16(wk0, xa[tt*2+0], accK[tt], 0,0,0);
    accK[tt] = __builtin_amdgcn_mfma_f32_16x16x32_bf16(wk1, xa[tt*2+1], accK[tt], 0,0,0);
  }
  accV = __builtin_amdgcn_mfma_f32_16x16x32_bf16(xa[w*2+0], wv0, accV, 0,0,0);
  accV = __builtin_amdgcn_mfma_f32_16x16x32_bf16(xa[w*2+1], wv1, accV, 0,0,0);

  // ---- Q^T tiles: C[e=quad*4+reg (+w*16)][Qrow=l16] -> Qfr frag bytes
  {
    const int e0 = w*16 + quad*4;
    const float b0 = bql[e0], b1 = bql[e0+1], b2 = bql[e0+2], b3 = bql[e0+3];
    const int qk = (e0 & 31) >> 3, hf = e0 >> 5, boff = (quad & 1) * 4;
    #pragma unroll
    for (int it = 0; it < 4; ++it){
      unsigned o = pack_fp8x4(accQ[it][0]+b0, accQ[it][1]+b1,
                              accQ[it][2]+b2, accQ[it][3]+b3);
      const int T = (r0 >> 4) + it;
      *(unsigned*)(Qfr + (size_t)h*((size_t)n<<6) + (size_t)T*1024
                       + (qk*16 + l16)*16 + hf*8 + boff) = o;
    }
  }
  // ---- K^T tiles: C[f=quad*4+reg (+w*16)][key=l16] -> Kt frag bytes
  {
    const int f0 = w*16 + quad*4;
    const float bk0 = bkl[f0], bk1 = bkl[f0+1], bk2 = bkl[f0+2], bk3 = bkl[f0+3];
    const int qk = (f0 & 31) >> 3, hf = f0 >> 5, boff = (quad & 1) * 4;
    #pragma unroll
    for (int tt = 0; tt < 4; ++tt){
      unsigned o = pack_fp8x4(accK[tt][0]+bk0, accK[tt][1]+bk1,
                              accK[tt][2]+bk2, accK[tt][3]+bk3);
      const int T = (r0 >> 4) + tt;
      *(unsigned*)(Kt + (size_t)h*((size_t)n<<6) + (size_t)T*1024
                      + (qk*16 + l16)*16 + hf*8 + boff) = o;
    }
  }
  // ---- V tile (it=w): C[key=quad*4+reg][d=l16] == Vt lane(quad,l16), j=reg.
  // Chunk-interleaved store: chunk C=T>>1, half=(T&1) -> 8B slot within the
  // lane's 16B K=32 frag.
  {
    float bvv = bvl[l16];
    unsigned v01 = pack2bf(accV[0]+bvv, accV[1]+bvv);
    unsigned v23 = pack2bf(accV[2]+bvv, accV[3]+bvv);
    const int T = (r0 >> 4) + w;
    *(uint2*)(Vt + (size_t)h*((size_t)n<<4)
                 + ((size_t)(T>>1)*64 + lane)*8 + (T&1)*4) = make_uint2(v01, v23);
  }
}

// ---------------- flash attention kernel ----------------
// R20: OCCUPANCY x2 (structure/numerics identical to R19 per wave).
// Post-mortem R15-R19: attn runs at the NO-OVERLAP bound -- measured time
// (106.5k cyc/SIMD) ~= matrix cycles (60k) + VALU/trans cycles (39k). The
// only variable that ever correlated with MFMA/VALU overlap is resident
// waves/SIMD (R15: 4.3 w/SIMD -> Mfma+VALU sum 111%; R18: 2.3 -> 94%).
// Work-trimming rounds were null because they shrank one term of a serial
// sum. So: same 64-row block, but 16 waves (1024 thr) with 16-way key split.
// Grid stays 512 -> 2 blocks/CU = 32 waves/CU = 8 waves/SIMD (hw cap).
// LDS: two-phase epilogue reduction (o then la through the same buffer)
// keeps part[] at 15*64*17 f32 = 65KB -> 2 blocks/CU fit.
// __launch_bounds__(1024,8) caps VGPR at 64 (body measured 52 -- no spill).
__global__ __launch_bounds__(1024, 8) void attn_kernel(
    const unsigned char* __restrict__ Qfr, const unsigned char* __restrict__ Kt,
    const unsigned short* __restrict__ Vt, float* __restrict__ out, int n)
{
  __shared__ float part[15][64][17];   // 65.3 KB, two-phase payload (16 f32)

  const int tid  = threadIdx.x;
  const int lane = tid & 63;
  const int jq   = tid >> 6;     // 0..15: key-range sixteenth

  // wave phase-stagger: ~190 cyc per step (mod 8), before any memory op.
  #pragma unroll 1
  for (int i = 0; i < (jq & 7); ++i) __builtin_amdgcn_s_sleep(3);

  const int bid  = blockIdx.x;
  const int h    = bid & 3;
  const int iblk = bid >> 2;
  const int l16  = lane & 15, quad = lane >> 4;
  const int i0   = iblk*64;
  const int ntq  = (n >> 4) >> 4;            // 16-key tiles per wave (32)
  const int nch  = ntq >> 1;                 // 32-key chunks per wave (16)
  const int tile0 = jq * ntq;

  // Q fragments: 4 i-tiles x 2 e-halves -- DENSE (one uint4 per i-tile)
  const unsigned char* qfh = Qfr + (size_t)h*((size_t)n<<6);
  longlong2 q0 = *(const longlong2*)(qfh + (size_t)((i0>>4)    )*1024 + lane*16);
  longlong2 q1 = *(const longlong2*)(qfh + (size_t)((i0>>4) + 1)*1024 + lane*16);
  longlong2 q2 = *(const longlong2*)(qfh + (size_t)((i0>>4) + 2)*1024 + lane*16);
  longlong2 q3 = *(const longlong2*)(qfh + (size_t)((i0>>4) + 3)*1024 + lane*16);
  const fp8x8 qf00 = (fp8x8)q0.x, qf01 = (fp8x8)q0.y;
  const fp8x8 qf10 = (fp8x8)q1.x, qf11 = (fp8x8)q1.y;
  const fp8x8 qf20 = (fp8x8)q2.x, qf21 = (fp8x8)q2.y;
  const fp8x8 qf30 = (fp8x8)q3.x, qf31 = (fp8x8)q3.y;

  const longlong2* ktl = (const longlong2*)(Kt + (size_t)h*((size_t)n<<6)) + (size_t)tile0*64 + lane;
  const uint4*     vtu = (const uint4*)(Vt + (size_t)h*((size_t)n<<4)) + (size_t)(tile0>>1)*64 + lane;

  const f32x4 z = {0.f,0.f,0.f,0.f};
  f32x4 o0 = z, o1 = z, o2 = z, o3 = z;
  f32x4 la0 = z, la1 = z, la2 = z, la3 = z;
  const bf16x8 vones = {(short)0x3F80, (short)0x3F80, (short)0x3F80, (short)0x3F80,
                        (short)0x3F80, (short)0x3F80, (short)0x3F80, (short)0x3F80};

  // prologue: chunk 0 in A regs, chunk 1 in B regs
  longlong2 ka0 = ktl[0],   ka1 = ktl[64];
  uint4     va  = vtu[0];
  longlong2 kb0 = ktl[128], kb1 = ktl[192];
  uint4     vb  = vtu[64];

// one i-tile granule: 4 QK MFMAs -> 8 exp2 -> 4 packs -> 2 PV MFMAs.
// Adjacent granules are fully independent (ILP for MFMA/VALU overlap).
#define ITILE(QA, QB, OO, LL)                                                 \
  {                                                                           \
    f32x4 s = __builtin_amdgcn_mfma_f32_16x16x32_fp8_fp8(a0, QA, z, 0,0,0);   \
    s = __builtin_amdgcn_mfma_f32_16x16x32_fp8_fp8(a1, QB, s, 0,0,0);         \
    f32x4 u = __builtin_amdgcn_mfma_f32_16x16x32_fp8_fp8(b0, QA, z, 0,0,0);   \
    u = __builtin_amdgcn_mfma_f32_16x16x32_fp8_fp8(b1, QB, u, 0,0,0);         \
    float e0 = __builtin_amdgcn_exp2f(s[0]);                                  \
    float e1 = __builtin_amdgcn_exp2f(s[1]);                                  \
    float e2 = __builtin_amdgcn_exp2f(s[2]);                                  \
    float e3 = __builtin_amdgcn_exp2f(s[3]);                                  \
    float f0 = __builtin_amdgcn_exp2f(u[0]);                                  \
    float f1 = __builtin_amdgcn_exp2f(u[1]);                                  \
    float f2 = __builtin_amdgcn_exp2f(u[2]);                                  \
    float f3 = __builtin_amdgcn_exp2f(u[3]);                                  \
    union { uint4 uu; bf16x8 v; } pq;                                         \
    pq.uu = make_uint4(pack2bf_t(e0,e1), pack2bf_t(e2,e3),                    \
                       pack2bf_t(f0,f1), pack2bf_t(f2,f3));                   \
    OO = __builtin_amdgcn_mfma_f32_16x16x32_bf16(pq.v, vfv,   OO, 0,0,0);     \
    LL = __builtin_amdgcn_mfma_f32_16x16x32_bf16(pq.v, vones, LL, 0,0,0);     \
  }

#define ATTN_CHUNK(KA, KB, VV)                                                \
  {                                                                           \
    const fp8x8 a0 = (fp8x8)KA.x, a1 = (fp8x8)KA.y;                           \
    const fp8x8 b0 = (fp8x8)KB.x, b1 = (fp8x8)KB.y;                           \
    union { uint4 uu; bf16x8 v; } vfu; vfu.uu = VV;                           \
    const bf16x8 vfv = vfu.v;                                                 \
    ITILE(qf00, qf01, o0, la0)                                                \
    ITILE(qf10, qf11, o1, la1)                                                \
    ITILE(qf20, qf21, o2, la2)                                                \
    ITILE(qf30, qf31, o3, la3)                                                \
  }

  // main loop, unrolled x2: process chunk c from A regs then reload A with
  // chunk c+2; same for B with c+1/c+3. No register moves.
  for (int c = 0; c < nch - 2; c += 2){
    ATTN_CHUNK(ka0, ka1, va)
    ka0 = ktl[256]; ka1 = ktl[320]; va = vtu[128];
    ATTN_CHUNK(kb0, kb1, vb)
    kb0 = ktl[384]; kb1 = ktl[448]; vb = vtu[192];
    ktl += 256; vtu += 128;
    // pipeline directive: per 2-chunk body, 48 MFMA : ~96 VALU arranged as
    // 16 x {3 MFMA, 6 VALU} -- keeps within-wave interleave; loads float.
    #pragma unroll
    for (int g = 0; g < 16; ++g){
      __builtin_amdgcn_sched_group_barrier(0x008, 3, 0);  // 3 MFMA
      __builtin_amdgcn_sched_group_barrier(0x002, 6, 0);  // 6 VALU
    }
  }
  // tail: last two chunks, no prefetch
  ATTN_CHUNK(ka0, ka1, va)
  ATTN_CHUNK(kb0, kb1, vb)
#undef ATTN_CHUNK
#undef ITILE

  // ---- two-phase cross-wave reduction (same LDS buffer reused) ----
  // Phase A: o partials.
  if (jq > 0){
    float* p = &part[jq-1][lane][0];
    p[ 0]=o0[0];  p[ 1]=o0[1];  p[ 2]=o0[2];  p[ 3]=o0[3];
    p[ 4]=o1[0];  p[ 5]=o1[1];  p[ 6]=o1[2];  p[ 7]=o1[3];
    p[ 8]=o2[0];  p[ 9]=o2[1];  p[10]=o2[2];  p[11]=o2[3];
    p[12]=o3[0];  p[13]=o3[1];  p[14]=o3[2];  p[15]=o3[3];
  }
  __syncthreads();
  if (jq == 0){
    #pragma unroll
    for (int q = 0; q < 15; ++q){
      const float* r = &part[q][lane][0];
      o0[0] +=r[0];  o0[1] +=r[1];  o0[2] +=r[2];  o0[3] +=r[3];
      o1[0] +=r[4];  o1[1] +=r[5];  o1[2] +=r[6];  o1[3] +=r[7];
      o2[0] +=r[8];  o2[1] +=r[9];  o2[2] +=r[10]; o2[3] +=r[11];
      o3[0] +=r[12]; o3[1] +=r[13]; o3[2] +=r[14]; o3[3] +=r[15];
    }
  }
  __syncthreads();
  // Phase B: la partials.
  if (jq > 0){
    float* p = &part[jq-1][lane][0];
    p[ 0]=la0[0]; p[ 1]=la0[1]; p[ 2]=la0[2]; p[ 3]=la0[3];
    p[ 4]=la1[0]; p[ 5]=la1[1]; p[ 6]=la1[2]; p[ 7]=la1[3];
    p[ 8]=la2[0]; p[ 9]=la2[1]; p[10]=la2[2]; p[11]=la2[3];
    p[12]=la3[0]; p[13]=la3[1]; p[14]=la3[2]; p[15]=la3[3];
  }
  __syncthreads();
  if (jq == 0){
    #pragma unroll
    for (int q = 0; q < 15; ++q){
      const float* r = &part[q][lane][0];
      la0[0]+=r[0];  la0[1]+=r[1];  la0[2]+=r[2];  la0[3]+=r[3];
      la1[0]+=r[4];  la1[1]+=r[5];  la1[2]+=r[6];  la1[3]+=r[7];
      la2[0]+=r[8];  la2[1]+=r[9];  la2[2]+=r[10]; la2[3]+=r[11];
      la3[0]+=r[12]; la3[1]+=r[13]; la3[2]+=r[14]; la3[3]+=r[15];
    }
    #pragma unroll
    for (int reg = 0; reg < 4; ++reg){
      int i = quad*4 + reg;
      out[(size_t)(i0 +      i)*64 + h*16 + l16] = o0[reg] / la0[reg];
      out[(size_t)(i0 + 16 + i)*64 + h*16 + l16] = o1[reg] / la1[reg];
      out[(size_t)(i0 + 32 + i)*64 + h*16 + l16] = o2[reg] / la2[reg];
      out[(size_t)(i0 + 48 + i)*64 + h*16 + l16] = o3[reg] / la3[reg];
    }
  }
}

extern "C" void kernel_launch(void* const* d_in, const int* in_sizes, int n_in,
                              void* d_out, int out_size, void* d_ws, size_t ws_size,
                              hipStream_t stream) {
  const float* x  = (const float*)d_in[0];
  const float* Wq = (const float*)d_in[1];
  const float* bq = (const float*)d_in[2];
  const float* Wk = (const float*)d_in[3];
  const float* bk = (const float*)d_in[4];
  const float* Wv = (const float*)d_in[5];
  const float* bv = (const float*)d_in[6];
  float* out = (float*)d_out;

  const int n = in_sizes[0] / 64;   // 8192

  unsigned char* Qfr  = (unsigned char*)d_ws;                       // NH*n*64 B frag tiles (Q)
  unsigned char* Kt   = Qfr + (size_t)NH*n*64;                      // NH*n*64 B frag tiles (K)
  unsigned short* Vt  = (unsigned short*)(Kt + (size_t)NH*n*64);    // NH*n*16 u16 frag tiles (chunk-interleaved)
  unsigned short* WF  = Vt + (size_t)NH*n*16;                       // NH*18*64*8 u16 frags
  float* bias_s       = (float*)(WF + (size_t)NH*18*64*8);          // NH*128 f32

  wprep_kernel<<<NH, 256, 0, stream>>>(Wq, bq, Wk, bk, Wv, WF, bias_s, n);
  proj_kernel<<<dim3(n/64, NH), 256, 0, stream>>>(x, bv, WF, bias_s, Qfr, Kt, Vt, n);
  attn_kernel<<<dim3((n/64)*NH), 1024, 0, stream>>>(Qfr, Kt, Vt, out, n);
}

// Round 6
// 128.640 us; speedup vs baseline: 2.8277x; 2.8277x over previous
//
#include <hip/hip_runtime.h>

typedef __attribute__((ext_vector_type(4))) float f32x4;
typedef __attribute__((ext_vector_type(8))) short bf16x8;
typedef __attribute__((ext_vector_type(4))) short bf16x4;
typedef long fp8x8;   // 8 packed e4m3 bytes (i64 MFMA operand)

#define NH 4

// round-to-nearest-even f32 -> bf16
static __device__ __forceinline__ unsigned short f2bf(float f){
  unsigned u = __float_as_uint(f);
  u += 0x7FFFu + ((u >> 16) & 1u);
  return (unsigned short)(u >> 16);
}

// pack two f32 -> two bf16 (round-half-up) in one uint (low = a)
static __device__ __forceinline__ unsigned pack2bf(float a, float b){
  return __builtin_amdgcn_perm(__float_as_uint(b) + 0x8000u,
                               __float_as_uint(a) + 0x8000u, 0x07060302u);
}

// pack two f32 -> two bf16 TRUNCATING (1 v_perm). Used only for P: the same
// truncated P feeds both O=P*V and l=P*1, so the truncation bias cancels.
static __device__ __forceinline__ unsigned pack2bf_t(float a, float b){
  return __builtin_amdgcn_perm(__float_as_uint(b), __float_as_uint(a), 0x07060302u);
}

// pack 4 floats into 4 fp8(e4m3) bytes of one int (byte0 = a)
static __device__ __forceinline__ int pack_fp8x4(float a, float b, float c, float d){
  int w = __builtin_amdgcn_cvt_pk_fp8_f32(a, b, 0, false);
  w     = __builtin_amdgcn_cvt_pk_fp8_f32(c, d, w, true);
  return w;
}

// ---------------- weight-prep kernel (runs once per launch, 4 blocks) ------
// Per head: builds bf16 MFMA fragment-order W in ws + scaled biases.
// WF[h][s][lane][8bf16]:
//   s 0..7  = Wq^T A-frags (s=et*2+ks, pre-scaled S1):
//             lane(quad,l16) = Wq[ks*32+quad*8+j][et*16+l16], j=0..7
//   s 8..15 = Wk^T A-frags (s-8=ft*2+ks, pre-scaled S1): same mapping
//   s 16,17 = Wv B-frags: lane(quad,l16) = Wv[ks*32+quad*8+j][l16]
// bias_s[h][0..63]=bq*S1, [64..127]=bk*S1.
__global__ __launch_bounds__(256) void wprep_kernel(
    const float* __restrict__ Wq, const float* __restrict__ bq,
    const float* __restrict__ Wk, const float* __restrict__ bk,
    const float* __restrict__ Wv,
    unsigned short* __restrict__ WF, float* __restrict__ bias_s, int n)
{
  __shared__ unsigned short wqT[64*72];  // [e][f], stride 72 (16B-aligned rows)
  __shared__ unsigned short wkT[64*72];
  __shared__ unsigned short wvT[16*72];  // [d][f]

  const int t = threadIdx.x;     // 0..255
  const int h = blockIdx.x;
  const float S1 = 0.4246609001f; // sqrt((1/sqrt(64)) * log2(e))
  const int f = t >> 2, eg = t & 3;

  {
    const float4* g = (const float4*)(Wq + h*4096 + f*64 + eg*16);
    #pragma unroll
    for (int p = 0; p < 4; ++p){
      float4 d = g[p];
      int e0 = eg*16 + p*4;
      wqT[(e0+0)*72 + f] = f2bf(d.x * S1);
      wqT[(e0+1)*72 + f] = f2bf(d.y * S1);
      wqT[(e0+2)*72 + f] = f2bf(d.z * S1);
      wqT[(e0+3)*72 + f] = f2bf(d.w * S1);
    }
  }
  {
    const float4* g = (const float4*)(Wk + h*4096 + f*64 + eg*16);
    #pragma unroll
    for (int p = 0; p < 4; ++p){
      float4 d = g[p];
      int e0 = eg*16 + p*4;
      wkT[(e0+0)*72 + f] = f2bf(d.x * S1);
      wkT[(e0+1)*72 + f] = f2bf(d.y * S1);
      wkT[(e0+2)*72 + f] = f2bf(d.z * S1);
      wkT[(e0+3)*72 + f] = f2bf(d.w * S1);
    }
  }
  {
    float4 d = *(const float4*)(Wv + h*1024 + f*16 + eg*4);
    int d0 = eg*4;
    wvT[(d0+0)*72 + f] = f2bf(d.x);
    wvT[(d0+1)*72 + f] = f2bf(d.y);
    wvT[(d0+2)*72 + f] = f2bf(d.z);
    wvT[(d0+3)*72 + f] = f2bf(d.w);
  }
  if (t < 64)       bias_s[h*128 + t] = bq[h*64 + t] * S1;
  else if (t < 128) bias_s[h*128 + t] = bk[h*64 + (t-64)] * S1;
  __syncthreads();

  const int lane = t & 63, w = t >> 6;
  const int quad = lane >> 4, l16 = lane & 15;
  for (int s = w; s < 18; s += 4){
    const unsigned short* src;
    if (s < 8){      int et = s>>1,     ks = s&1;     src = wqT + (et*16+l16)*72 + ks*32 + quad*8; }
    else if (s < 16){int ft = (s-8)>>1, ks = (s-8)&1; src = wkT + (ft*16+l16)*72 + ks*32 + quad*8; }
    else {           int ks = s-16;                   src = wvT + l16*72 + ks*32 + quad*8; }
    uint4 v = *(const uint4*)src;
    *(uint4*)(WF + ((size_t)(h*18 + s)*64 + lane)*8) = v;
  }
}

// ---------------- projection kernel (MFMA) ----------------
// grid (n/64, NH), block 256 = 4 waves. Per wave: Q^T (e-tile w, 4 row-tiles),
// K^T (f-tile w, 4 key-tiles), V (row-tile w). Epilogue writes Qfr/Kt/Vt in
// fragment-tile order so ALL attn hot/prologue loads are dense.
// Vt is written CHUNK-interleaved (chunk C = pair of 16-key tiles):
// lane frag of tile T lands at (C*64+lane)*16B + (T&1)*8B, so attn's K=32 PV
// B-operand (32-key V frag) is ONE dense 16B load per lane.
__global__ __launch_bounds__(256) void proj_kernel(
    const float* __restrict__ x, const float* __restrict__ bv,
    const unsigned short* __restrict__ WF, const float* __restrict__ bias_s,
    unsigned char* __restrict__ Qfr, unsigned char* __restrict__ Kt,
    unsigned short* __restrict__ Vt, int n)
{
  __shared__ unsigned short xf[8*64*8];  // x frags: [it*2+ks][lane][8bf16]
  __shared__ float bql[64], bkl[64], bvl[16];

  const int t  = threadIdx.x;
  const int h  = blockIdx.y;
  const int r0 = blockIdx.x * 64;

  // stage x tile -> bf16 fragment order
  {
    const int r = t >> 2, cg4 = t & 3;
    const float4* g = (const float4*)(x + (size_t)(r0 + r)*64 + cg4*16);
    float4 a = g[0], b = g[1], c = g[2], d = g[3];
    unsigned u0 = pack2bf(a.x,a.y), u1 = pack2bf(a.z,a.w);
    unsigned u2 = pack2bf(b.x,b.y), u3 = pack2bf(b.z,b.w);
    unsigned u4 = pack2bf(c.x,c.y), u5 = pack2bf(c.z,c.w);
    unsigned u6 = pack2bf(d.x,d.y), u7 = pack2bf(d.z,d.w);
    const int it = r >> 4, l16r = r & 15, ks = cg4 >> 1, q0 = (cg4 & 1)*2;
    uint4* dst0 = (uint4*)(xf + ((it*2+ks)*64 + q0*16     + l16r)*8);
    uint4* dst1 = (uint4*)(xf + ((it*2+ks)*64 + (q0+1)*16 + l16r)*8);
    *dst0 = make_uint4(u0,u1,u2,u3);
    *dst1 = make_uint4(u4,u5,u6,u7);
  }
  if (t < 64)        bql[t]     = bias_s[h*128 + t];
  else if (t < 128)  bkl[t-64]  = bias_s[h*128 + t];
  else if (t < 144)  bvl[t-128] = bv[h*16 + (t-128)];
  __syncthreads();

  const int lane = t & 63, w = t >> 6;
  const int quad = lane >> 4, l16 = lane & 15;

  bf16x8 xa[8];
  #pragma unroll
  for (int i = 0; i < 8; ++i)
    xa[i] = *(const bf16x8*)(xf + (i*64 + lane)*8);

  const unsigned short* WFh = WF + (size_t)h*18*64*8;
  bf16x8 wq0 = *(const bf16x8*)(WFh + ((size_t)(     w*2 + 0)*64 + lane)*8);
  bf16x8 wq1 = *(const bf16x8*)(WFh + ((size_t)(     w*2 + 1)*64 + lane)*8);
  bf16x8 wk0 = *(const bf16x8*)(WFh + ((size_t)(8  + w*2 + 0)*64 + lane)*8);
  bf16x8 wk1 = *(const bf16x8*)(WFh + ((size_t)(8  + w*2 + 1)*64 + lane)*8);
  bf16x8 wv0 = *(const bf16x8*)(WFh + ((size_t)16*64 + lane)*8);
  bf16x8 wv1 = *(const bf16x8*)(WFh + ((size_t)17*64 + lane)*8);

  const f32x4 z = {0.f,0.f,0.f,0.f};
  f32x4 accQ[4] = {z,z,z,z};   // Q^T: rows e (tile w), cols Q-row (tile it)
  f32x4 accK[4] = {z,z,z,z};   // K^T: rows f (tile w), cols key (tile tt)
  f32x4 accV = z;

  #pragma unroll
  for (int it = 0; it < 4; ++it){
    accQ[it] = __builtin_amdgcn_mfma_f32_16x16x32_bf16(wq0, xa[it*2+0], accQ[it], 0,0,0);
    accQ[it] = __builtin_amdgcn_mfma_f32_16x16x32_bf16(wq1, xa[it*2+1], accQ[it], 0,0,0);
  }
  #pragma unroll
  for (int tt = 0; tt < 4; ++tt){
    accK[tt] = __builtin_amdgcn_mfma_f32_16x16x32_bf16(wk0, xa[tt*2+0], accK[tt], 0,0,0);
    accK[tt] = __builtin_amdgcn_mfma_f32_16x16x32_bf16(wk1, xa[tt*2+1], accK[tt], 0,0,0);
  }
  accV = __builtin_amdgcn_mfma_f32_16x16x32_bf16(xa[w*2+0], wv0, accV, 0,0,0);
  accV = __builtin_amdgcn_mfma_f32_16x16x32_bf16(xa[w*2+1], wv1, accV, 0,0,0);

  // ---- Q^T tiles: C[e=quad*4+reg (+w*16)][Qrow=l16] -> Qfr frag bytes
  {
    const int e0 = w*16 + quad*4;
    const float b0 = bql[e0], b1 = bql[e0+1], b2 = bql[e0+2], b3 = bql[e0+3];
    const int qk = (e0 & 31) >> 3, hf = e0 >> 5, boff = (quad & 1) * 4;
    #pragma unroll
    for (int it = 0; it < 4; ++it){
      unsigned o = pack_fp8x4(accQ[it][0]+b0, accQ[it][1]+b1,
                              accQ[it][2]+b2, accQ[it][3]+b3);
      const int T = (r0 >> 4) + it;
      *(unsigned*)(Qfr + (size_t)h*((size_t)n<<6) + (size_t)T*1024
                       + (qk*16 + l16)*16 + hf*8 + boff) = o;
    }
  }
  // ---- K^T tiles: C[f=quad*4+reg (+w*16)][key=l16] -> Kt frag bytes
  {
    const int f0 = w*16 + quad*4;
    const float bk0 = bkl[f0], bk1 = bkl[f0+1], bk2 = bkl[f0+2], bk3 = bkl[f0+3];
    const int qk = (f0 & 31) >> 3, hf = f0 >> 5, boff = (quad & 1) * 4;
    #pragma unroll
    for (int tt = 0; tt < 4; ++tt){
      unsigned o = pack_fp8x4(accK[tt][0]+bk0, accK[tt][1]+bk1,
                              accK[tt][2]+bk2, accK[tt][3]+bk3);
      const int T = (r0 >> 4) + tt;
      *(unsigned*)(Kt + (size_t)h*((size_t)n<<6) + (size_t)T*1024
                      + (qk*16 + l16)*16 + hf*8 + boff) = o;
    }
  }
  // ---- V tile (it=w): C[key=quad*4+reg][d=l16] == Vt lane(quad,l16), j=reg.
  // Chunk-interleaved store: chunk C=T>>1, half=(T&1) -> 8B slot within the
  // lane's 16B K=32 frag.
  {
    float bvv = bvl[l16];
    unsigned v01 = pack2bf(accV[0]+bvv, accV[1]+bvv);
    unsigned v23 = pack2bf(accV[2]+bvv, accV[3]+bvv);
    const int T = (r0 >> 4) + w;
    *(uint2*)(Vt + (size_t)h*((size_t)n<<4)
                 + ((size_t)(T>>1)*64 + lane)*8 + (T&1)*4) = make_uint2(v01, v23);
  }
}

// ---------------- flash attention kernel ----------------
// R21: OCCUPANCY x2, SPILL-FIXED RETRY of R20. R20's __launch_bounds__(1024,8)
// strangled the allocator (VGPR_Count 32 for a ~52-VGPR body) -> massive
// scratch spill (FETCH 427MB/dispatch, 8x slowdown). The occupancy hypothesis
// was never tested. Fix: __launch_bounds__(1024, 4) -- budget 128, body
// compiles at its natural ~52-64 VGPR, and runtime residency is then set by
// actual VGPR (<=64 -> 8 waves/SIMD) and LDS (2 x 65KB <= 160KB -> 2 blocks).
// Hypothesis under test (from R15-R19): attn runs at the NO-OVERLAP bound
// (time ~ MFMA-cyc + VALU-cyc ~ 106k/SIMD); overlap has only ever tracked
// resident waves/SIMD. 16 waves/block, 16-way key split, grid 512
// -> 2 blocks/CU = 32 waves/CU = 8 waves/SIMD (vs R19's 4).
// Outcomes: (a) attn 31-37us -> lever confirmed; (b) attn ~44 + no spill ->
// occupancy falsified twice, pivot to wave specialization; (c) VGPR>64 ->
// 1 block/CU = R19-equivalent, no harm.
__global__ __launch_bounds__(1024, 4) void attn_kernel(
    const unsigned char* __restrict__ Qfr, const unsigned char* __restrict__ Kt,
    const unsigned short* __restrict__ Vt, float* __restrict__ out, int n)
{
  __shared__ float part[15][64][17];   // 65.3 KB, two-phase payload (16 f32)

  const int tid  = threadIdx.x;
  const int lane = tid & 63;
  const int jq   = tid >> 6;     // 0..15: key-range sixteenth

  // wave phase-stagger: ~190 cyc per step (mod 8), before any memory op.
  #pragma unroll 1
  for (int i = 0; i < (jq & 7); ++i) __builtin_amdgcn_s_sleep(3);

  const int bid  = blockIdx.x;
  const int h    = bid & 3;
  const int iblk = bid >> 2;
  const int l16  = lane & 15, quad = lane >> 4;
  const int i0   = iblk*64;
  const int ntq  = (n >> 4) >> 4;            // 16-key tiles per wave (32)
  const int nch  = ntq >> 1;                 // 32-key chunks per wave (16)
  const int tile0 = jq * ntq;

  // Q fragments: 4 i-tiles x 2 e-halves -- DENSE (one uint4 per i-tile)
  const unsigned char* qfh = Qfr + (size_t)h*((size_t)n<<6);
  longlong2 q0 = *(const longlong2*)(qfh + (size_t)((i0>>4)    )*1024 + lane*16);
  longlong2 q1 = *(const longlong2*)(qfh + (size_t)((i0>>4) + 1)*1024 + lane*16);
  longlong2 q2 = *(const longlong2*)(qfh + (size_t)((i0>>4) + 2)*1024 + lane*16);
  longlong2 q3 = *(const longlong2*)(qfh + (size_t)((i0>>4) + 3)*1024 + lane*16);
  const fp8x8 qf00 = (fp8x8)q0.x, qf01 = (fp8x8)q0.y;
  const fp8x8 qf10 = (fp8x8)q1.x, qf11 = (fp8x8)q1.y;
  const fp8x8 qf20 = (fp8x8)q2.x, qf21 = (fp8x8)q2.y;
  const fp8x8 qf30 = (fp8x8)q3.x, qf31 = (fp8x8)q3.y;

  const longlong2* ktl = (const longlong2*)(Kt + (size_t)h*((size_t)n<<6)) + (size_t)tile0*64 + lane;
  const uint4*     vtu = (const uint4*)(Vt + (size_t)h*((size_t)n<<4)) + (size_t)(tile0>>1)*64 + lane;

  const f32x4 z = {0.f,0.f,0.f,0.f};
  f32x4 o0 = z, o1 = z, o2 = z, o3 = z;
  f32x4 la0 = z, la1 = z, la2 = z, la3 = z;
  const bf16x8 vones = {(short)0x3F80, (short)0x3F80, (short)0x3F80, (short)0x3F80,
                        (short)0x3F80, (short)0x3F80, (short)0x3F80, (short)0x3F80};

  // prologue: chunk 0 in A regs, chunk 1 in B regs
  longlong2 ka0 = ktl[0],   ka1 = ktl[64];
  uint4     va  = vtu[0];
  longlong2 kb0 = ktl[128], kb1 = ktl[192];
  uint4     vb  = vtu[64];

// one i-tile granule: 4 QK MFMAs -> 8 exp2 -> 4 packs -> 2 PV MFMAs.
// Adjacent granules are fully independent (ILP for MFMA/VALU overlap).
#define ITILE(QA, QB, OO, LL)                                                 \
  {                                                                           \
    f32x4 s = __builtin_amdgcn_mfma_f32_16x16x32_fp8_fp8(a0, QA, z, 0,0,0);   \
    s = __builtin_amdgcn_mfma_f32_16x16x32_fp8_fp8(a1, QB, s, 0,0,0);         \
    f32x4 u = __builtin_amdgcn_mfma_f32_16x16x32_fp8_fp8(b0, QA, z, 0,0,0);   \
    u = __builtin_amdgcn_mfma_f32_16x16x32_fp8_fp8(b1, QB, u, 0,0,0);         \
    float e0 = __builtin_amdgcn_exp2f(s[0]);                                  \
    float e1 = __builtin_amdgcn_exp2f(s[1]);                                  \
    float e2 = __builtin_amdgcn_exp2f(s[2]);                                  \
    float e3 = __builtin_amdgcn_exp2f(s[3]);                                  \
    float f0 = __builtin_amdgcn_exp2f(u[0]);                                  \
    float f1 = __builtin_amdgcn_exp2f(u[1]);                                  \
    float f2 = __builtin_amdgcn_exp2f(u[2]);                                  \
    float f3 = __builtin_amdgcn_exp2f(u[3]);                                  \
    union { uint4 uu; bf16x8 v; } pq;                                         \
    pq.uu = make_uint4(pack2bf_t(e0,e1), pack2bf_t(e2,e3),                    \
                       pack2bf_t(f0,f1), pack2bf_t(f2,f3));                   \
    OO = __builtin_amdgcn_mfma_f32_16x16x32_bf16(pq.v, vfv,   OO, 0,0,0);     \
    LL = __builtin_amdgcn_mfma_f32_16x16x32_bf16(pq.v, vones, LL, 0,0,0);     \
  }

#define ATTN_CHUNK(KA, KB, VV)                                                \
  {                                                                           \
    const fp8x8 a0 = (fp8x8)KA.x, a1 = (fp8x8)KA.y;                           \
    const fp8x8 b0 = (fp8x8)KB.x, b1 = (fp8x8)KB.y;                           \
    union { uint4 uu; bf16x8 v; } vfu; vfu.uu = VV;                           \
    const bf16x8 vfv = vfu.v;                                                 \
    ITILE(qf00, qf01, o0, la0)                                                \
    ITILE(qf10, qf11, o1, la1)                                                \
    ITILE(qf20, qf21, o2, la2)                                                \
    ITILE(qf30, qf31, o3, la3)                                                \
  }

  // main loop, unrolled x2: process chunk c from A regs then reload A with
  // chunk c+2; same for B with c+1/c+3. No register moves.
  for (int c = 0; c < nch - 2; c += 2){
    ATTN_CHUNK(ka0, ka1, va)
    ka0 = ktl[256]; ka1 = ktl[320]; va = vtu[128];
    ATTN_CHUNK(kb0, kb1, vb)
    kb0 = ktl[384]; kb1 = ktl[448]; vb = vtu[192];
    ktl += 256; vtu += 128;
    // pipeline directive: per 2-chunk body, 48 MFMA : ~96 VALU arranged as
    // 16 x {3 MFMA, 6 VALU} -- keeps within-wave interleave; loads float.
    #pragma unroll
    for (int g = 0; g < 16; ++g){
      __builtin_amdgcn_sched_group_barrier(0x008, 3, 0);  // 3 MFMA
      __builtin_amdgcn_sched_group_barrier(0x002, 6, 0);  // 6 VALU
    }
  }
  // tail: last two chunks, no prefetch
  ATTN_CHUNK(ka0, ka1, va)
  ATTN_CHUNK(kb0, kb1, vb)
#undef ATTN_CHUNK
#undef ITILE

  // ---- two-phase cross-wave reduction (same LDS buffer reused) ----
  // Phase A: o partials.
  if (jq > 0){
    float* p = &part[jq-1][lane][0];
    p[ 0]=o0[0];  p[ 1]=o0[1];  p[ 2]=o0[2];  p[ 3]=o0[3];
    p[ 4]=o1[0];  p[ 5]=o1[1];  p[ 6]=o1[2];  p[ 7]=o1[3];
    p[ 8]=o2[0];  p[ 9]=o2[1];  p[10]=o2[2];  p[11]=o2[3];
    p[12]=o3[0];  p[13]=o3[1];  p[14]=o3[2];  p[15]=o3[3];
  }
  __syncthreads();
  if (jq == 0){
    #pragma unroll
    for (int q = 0; q < 15; ++q){
      const float* r = &part[q][lane][0];
      o0[0] +=r[0];  o0[1] +=r[1];  o0[2] +=r[2];  o0[3] +=r[3];
      o1[0] +=r[4];  o1[1] +=r[5];  o1[2] +=r[6];  o1[3] +=r[7];
      o2[0] +=r[8];  o2[1] +=r[9];  o2[2] +=r[10]; o2[3] +=r[11];
      o3[0] +=r[12]; o3[1] +=r[13]; o3[2] +=r[14]; o3[3] +=r[15];
    }
  }
  __syncthreads();
  // Phase B: la partials.
  if (jq > 0){
    float* p = &part[jq-1][lane][0];
    p[ 0]=la0[0]; p[ 1]=la0[1]; p[ 2]=la0[2]; p[ 3]=la0[3];
    p[ 4]=la1[0]; p[ 5]=la1[1]; p[ 6]=la1[2]; p[ 7]=la1[3];
    p[ 8]=la2[0]; p[ 9]=la2[1]; p[10]=la2[2]; p[11]=la2[3];
    p[12]=la3[0]; p[13]=la3[1]; p[14]=la3[2]; p[15]=la3[3];
  }
  __syncthreads();
  if (jq == 0){
    #pragma unroll
    for (int q = 0; q < 15; ++q){
      const float* r = &part[q][lane][0];
      la0[0]+=r[0];  la0[1]+=r[1];  la0[2]+=r[2];  la0[3]+=r[3];
      la1[0]+=r[4];  la1[1]+=r[5];  la1[2]+=r[6];  la1[3]+=r[7];
      la2[0]+=r[8];  la2[1]+=r[9];  la2[2]+=r[10]; la2[3]+=r[11];
      la3[0]+=r[12]; la3[1]+=r[13]; la3[2]+=r[14]; la3[3]+=r[15];
    }
    #pragma unroll
    for (int reg = 0; reg < 4; ++reg){
      int i = quad*4 + reg;
      out[(size_t)(i0 +      i)*64 + h*16 + l16] = o0[reg] / la0[reg];
      out[(size_t)(i0 + 16 + i)*64 + h*16 + l16] = o1[reg] / la1[reg];
      out[(size_t)(i0 + 32 + i)*64 + h*16 + l16] = o2[reg] / la2[reg];
      out[(size_t)(i0 + 48 + i)*64 + h*16 + l16] = o3[reg] / la3[reg];
    }
  }
}

extern "C" void kernel_launch(void* const* d_in, const int* in_sizes, int n_in,
                              void* d_out, int out_size, void* d_ws, size_t ws_size,
                              hipStream_t stream) {
  const float* x  = (const float*)d_in[0];
  const float* Wq = (const float*)d_in[1];
  const float* bq = (const float*)d_in[2];
  const float* Wk = (const float*)d_in[3];
  const float* bk = (const float*)d_in[4];
  const float* Wv = (const float*)d_in[5];
  const float* bv = (const float*)d_in[6];
  float* out = (float*)d_out;

  const int n = in_sizes[0] / 64;   // 8192

  unsigned char* Qfr  = (unsigned char*)d_ws;                       // NH*n*64 B frag tiles (Q)
  unsigned char* Kt   = Qfr + (size_t)NH*n*64;                      // NH*n*64 B frag tiles (K)
  unsigned short* Vt  = (unsigned short*)(Kt + (size_t)NH*n*64);    // NH*n*16 u16 frag tiles (chunk-interleaved)
  unsigned short* WF  = Vt + (size_t)NH*n*16;                       // NH*18*64*8 u16 frags
  float* bias_s       = (float*)(WF + (size_t)NH*18*64*8);          // NH*128 f32

  wprep_kernel<<<NH, 256, 0, stream>>>(Wq, bq, Wk, bk, Wv, WF, bias_s, n);
  proj_kernel<<<dim3(n/64, NH), 256, 0, stream>>>(x, bv, WF, bias_s, Qfr, Kt, Vt, n);
  attn_kernel<<<dim3((n/64)*NH), 1024, 0, stream>>>(Qfr, Kt, Vt, out, n);
}

// Round 7
// 118.527 us; speedup vs baseline: 3.0690x; 1.0853x over previous
//
#include <hip/hip_runtime.h>

typedef __attribute__((ext_vector_type(4))) float f32x4;
typedef __attribute__((ext_vector_type(8))) short bf16x8;
typedef __attribute__((ext_vector_type(4))) short bf16x4;
typedef long fp8x8;   // 8 packed e4m3 bytes (i64 MFMA operand)

#define NH 4

// round-to-nearest-even f32 -> bf16
static __device__ __forceinline__ unsigned short f2bf(float f){
  unsigned u = __float_as_uint(f);
  u += 0x7FFFu + ((u >> 16) & 1u);
  return (unsigned short)(u >> 16);
}

// pack two f32 -> two bf16 (round-half-up) in one uint (low = a)
static __device__ __forceinline__ unsigned pack2bf(float a, float b){
  return __builtin_amdgcn_perm(__float_as_uint(b) + 0x8000u,
                               __float_as_uint(a) + 0x8000u, 0x07060302u);
}

// pack two f32 -> two bf16 TRUNCATING (1 v_perm). Used only for P: the same
// truncated P feeds both O=P*V and l=P*1, so the truncation bias cancels.
static __device__ __forceinline__ unsigned pack2bf_t(float a, float b){
  return __builtin_amdgcn_perm(__float_as_uint(b), __float_as_uint(a), 0x07060302u);
}

// pack 4 floats into 4 fp8(e4m3) bytes of one int (byte0 = a)
static __device__ __forceinline__ int pack_fp8x4(float a, float b, float c, float d){
  int w = __builtin_amdgcn_cvt_pk_fp8_f32(a, b, 0, false);
  w     = __builtin_amdgcn_cvt_pk_fp8_f32(c, d, w, true);
  return w;
}

// ---------------- weight-prep kernel (runs once per launch, 4 blocks) ------
// Per head: builds bf16 MFMA fragment-order W in ws + scaled biases.
// WF[h][s][lane][8bf16]:
//   s 0..7  = Wq^T A-frags (s=et*2+ks, pre-scaled S1):
//             lane(quad,l16) = Wq[ks*32+quad*8+j][et*16+l16], j=0..7
//   s 8..15 = Wk^T A-frags (s-8=ft*2+ks, pre-scaled S1): same mapping
//   s 16,17 = Wv B-frags: lane(quad,l16) = Wv[ks*32+quad*8+j][l16]
// bias_s[h][0..63]=bq*S1, [64..127]=bk*S1.
__global__ __launch_bounds__(256) void wprep_kernel(
    const float* __restrict__ Wq, const float* __restrict__ bq,
    const float* __restrict__ Wk, const float* __restrict__ bk,
    const float* __restrict__ Wv,
    unsigned short* __restrict__ WF, float* __restrict__ bias_s, int n)
{
  __shared__ unsigned short wqT[64*72];  // [e][f], stride 72 (16B-aligned rows)
  __shared__ unsigned short wkT[64*72];
  __shared__ unsigned short wvT[16*72];  // [d][f]

  const int t = threadIdx.x;     // 0..255
  const int h = blockIdx.x;
  const float S1 = 0.4246609001f; // sqrt((1/sqrt(64)) * log2(e))
  const int f = t >> 2, eg = t & 3;

  {
    const float4* g = (const float4*)(Wq + h*4096 + f*64 + eg*16);
    #pragma unroll
    for (int p = 0; p < 4; ++p){
      float4 d = g[p];
      int e0 = eg*16 + p*4;
      wqT[(e0+0)*72 + f] = f2bf(d.x * S1);
      wqT[(e0+1)*72 + f] = f2bf(d.y * S1);
      wqT[(e0+2)*72 + f] = f2bf(d.z * S1);
      wqT[(e0+3)*72 + f] = f2bf(d.w * S1);
    }
  }
  {
    const float4* g = (const float4*)(Wk + h*4096 + f*64 + eg*16);
    #pragma unroll
    for (int p = 0; p < 4; ++p){
      float4 d = g[p];
      int e0 = eg*16 + p*4;
      wkT[(e0+0)*72 + f] = f2bf(d.x * S1);
      wkT[(e0+1)*72 + f] = f2bf(d.y * S1);
      wkT[(e0+2)*72 + f] = f2bf(d.z * S1);
      wkT[(e0+3)*72 + f] = f2bf(d.w * S1);
    }
  }
  {
    float4 d = *(const float4*)(Wv + h*1024 + f*16 + eg*4);
    int d0 = eg*4;
    wvT[(d0+0)*72 + f] = f2bf(d.x);
    wvT[(d0+1)*72 + f] = f2bf(d.y);
    wvT[(d0+2)*72 + f] = f2bf(d.z);
    wvT[(d0+3)*72 + f] = f2bf(d.w);
  }
  if (t < 64)       bias_s[h*128 + t] = bq[h*64 + t] * S1;
  else if (t < 128) bias_s[h*128 + t] = bk[h*64 + (t-64)] * S1;
  __syncthreads();

  const int lane = t & 63, w = t >> 6;
  const int quad = lane >> 4, l16 = lane & 15;
  for (int s = w; s < 18; s += 4){
    const unsigned short* src;
    if (s < 8){      int et = s>>1,     ks = s&1;     src = wqT + (et*16+l16)*72 + ks*32 + quad*8; }
    else if (s < 16){int ft = (s-8)>>1, ks = (s-8)&1; src = wkT + (ft*16+l16)*72 + ks*32 + quad*8; }
    else {           int ks = s-16;                   src = wvT + l16*72 + ks*32 + quad*8; }
    uint4 v = *(const uint4*)src;
    *(uint4*)(WF + ((size_t)(h*18 + s)*64 + lane)*8) = v;
  }
}

// ---------------- projection kernel (MFMA) ----------------
// grid (n/64, NH), block 256 = 4 waves. Per wave: Q^T (e-tile w, 4 row-tiles),
// K^T (f-tile w, 4 key-tiles), V (row-tile w). Epilogue writes Qfr/Kt/Vt in
// fragment-tile order so ALL attn hot/prologue loads are dense.
// Vt is written CHUNK-interleaved (chunk C = pair of 16-key tiles):
// lane frag of tile T lands at (C*64+lane)*16B + (T&1)*8B, so attn's K=32 PV
// B-operand (32-key V frag) is ONE dense 16B load per lane.
__global__ __launch_bounds__(256) void proj_kernel(
    const float* __restrict__ x, const float* __restrict__ bv,
    const unsigned short* __restrict__ WF, const float* __restrict__ bias_s,
    unsigned char* __restrict__ Qfr, unsigned char* __restrict__ Kt,
    unsigned short* __restrict__ Vt, int n)
{
  __shared__ unsigned short xf[8*64*8];  // x frags: [it*2+ks][lane][8bf16]
  __shared__ float bql[64], bkl[64], bvl[16];

  const int t  = threadIdx.x;
  const int h  = blockIdx.y;
  const int r0 = blockIdx.x * 64;

  // stage x tile -> bf16 fragment order
  {
    const int r = t >> 2, cg4 = t & 3;
    const float4* g = (const float4*)(x + (size_t)(r0 + r)*64 + cg4*16);
    float4 a = g[0], b = g[1], c = g[2], d = g[3];
    unsigned u0 = pack2bf(a.x,a.y), u1 = pack2bf(a.z,a.w);
    unsigned u2 = pack2bf(b.x,b.y), u3 = pack2bf(b.z,b.w);
    unsigned u4 = pack2bf(c.x,c.y), u5 = pack2bf(c.z,c.w);
    unsigned u6 = pack2bf(d.x,d.y), u7 = pack2bf(d.z,d.w);
    const int it = r >> 4, l16r = r & 15, ks = cg4 >> 1, q0 = (cg4 & 1)*2;
    uint4* dst0 = (uint4*)(xf + ((it*2+ks)*64 + q0*16     + l16r)*8);
    uint4* dst1 = (uint4*)(xf + ((it*2+ks)*64 + (q0+1)*16 + l16r)*8);
    *dst0 = make_uint4(u0,u1,u2,u3);
    *dst1 = make_uint4(u4,u5,u6,u7);
  }
  if (t < 64)        bql[t]     = bias_s[h*128 + t];
  else if (t < 128)  bkl[t-64]  = bias_s[h*128 + t];
  else if (t < 144)  bvl[t-128] = bv[h*16 + (t-128)];
  __syncthreads();

  const int lane = t & 63, w = t >> 6;
  const int quad = lane >> 4, l16 = lane & 15;

  bf16x8 xa[8];
  #pragma unroll
  for (int i = 0; i < 8; ++i)
    xa[i] = *(const bf16x8*)(xf + (i*64 + lane)*8);

  const unsigned short* WFh = WF + (size_t)h*18*64*8;
  bf16x8 wq0 = *(const bf16x8*)(WFh + ((size_t)(     w*2 + 0)*64 + lane)*8);
  bf16x8 wq1 = *(const bf16x8*)(WFh + ((size_t)(     w*2 + 1)*64 + lane)*8);
  bf16x8 wk0 = *(const bf16x8*)(WFh + ((size_t)(8  + w*2 + 0)*64 + lane)*8);
  bf16x8 wk1 = *(const bf16x8*)(WFh + ((size_t)(8  + w*2 + 1)*64 + lane)*8);
  bf16x8 wv0 = *(const bf16x8*)(WFh + ((size_t)16*64 + lane)*8);
  bf16x8 wv1 = *(const bf16x8*)(WFh + ((size_t)17*64 + lane)*8);

  const f32x4 z = {0.f,0.f,0.f,0.f};
  f32x4 accQ[4] = {z,z,z,z};   // Q^T: rows e (tile w), cols Q-row (tile it)
  f32x4 accK[4] = {z,z,z,z};   // K^T: rows f (tile w), cols key (tile tt)
  f32x4 accV = z;

  #pragma unroll
  for (int it = 0; it < 4; ++it){
    accQ[it] = __builtin_amdgcn_mfma_f32_16x16x32_bf16(wq0, xa[it*2+0], accQ[it], 0,0,0);
    accQ[it] = __builtin_amdgcn_mfma_f32_16x16x32_bf16(wq1, xa[it*2+1], accQ[it], 0,0,0);
  }
  #pragma unroll
  for (int tt = 0; tt < 4; ++tt){
    accK[tt] = __builtin_amdgcn_mfma_f32_16x16x32_bf16(wk0, xa[tt*2+0], accK[tt], 0,0,0);
    accK[tt] = __builtin_amdgcn_mfma_f32_16x16x32_bf16(wk1, xa[tt*2+1], accK[tt], 0,0,0);
  }
  accV = __builtin_amdgcn_mfma_f32_16x16x32_bf16(xa[w*2+0], wv0, accV, 0,0,0);
  accV = __builtin_amdgcn_mfma_f32_16x16x32_bf16(xa[w*2+1], wv1, accV, 0,0,0);

  // ---- Q^T tiles: C[e=quad*4+reg (+w*16)][Qrow=l16] -> Qfr frag bytes
  {
    const int e0 = w*16 + quad*4;
    const float b0 = bql[e0], b1 = bql[e0+1], b2 = bql[e0+2], b3 = bql[e0+3];
    const int qk = (e0 & 31) >> 3, hf = e0 >> 5, boff = (quad & 1) * 4;
    #pragma unroll
    for (int it = 0; it < 4; ++it){
      unsigned o = pack_fp8x4(accQ[it][0]+b0, accQ[it][1]+b1,
                              accQ[it][2]+b2, accQ[it][3]+b3);
      const int T = (r0 >> 4) + it;
      *(unsigned*)(Qfr + (size_t)h*((size_t)n<<6) + (size_t)T*1024
                       + (qk*16 + l16)*16 + hf*8 + boff) = o;
    }
  }
  // ---- K^T tiles: C[f=quad*4+reg (+w*16)][key=l16] -> Kt frag bytes
  {
    const int f0 = w*16 + quad*4;
    const float bk0 = bkl[f0], bk1 = bkl[f0+1], bk2 = bkl[f0+2], bk3 = bkl[f0+3];
    const int qk = (f0 & 31) >> 3, hf = f0 >> 5, boff = (quad & 1) * 4;
    #pragma unroll
    for (int tt = 0; tt < 4; ++tt){
      unsigned o = pack_fp8x4(accK[tt][0]+bk0, accK[tt][1]+bk1,
                              accK[tt][2]+bk2, accK[tt][3]+bk3);
      const int T = (r0 >> 4) + tt;
      *(unsigned*)(Kt + (size_t)h*((size_t)n<<6) + (size_t)T*1024
                      + (qk*16 + l16)*16 + hf*8 + boff) = o;
    }
  }
  // ---- V tile (it=w): C[key=quad*4+reg][d=l16] == Vt lane(quad,l16), j=reg.
  // Chunk-interleaved store: chunk C=T>>1, half=(T&1) -> 8B slot within the
  // lane's 16B K=32 frag.
  {
    float bvv = bvl[l16];
    unsigned v01 = pack2bf(accV[0]+bvv, accV[1]+bvv);
    unsigned v23 = pack2bf(accV[2]+bvv, accV[3]+bvv);
    const int T = (r0 >> 4) + w;
    *(uint2*)(Vt + (size_t)h*((size_t)n<<4)
                 + ((size_t)(T>>1)*64 + lane)*8 + (T&1)*4) = make_uint2(v01, v23);
  }
}

// ---------------- flash attention kernel ----------------
// R22: REVERT to R19 (best verified: attn 44.4us) + corrected SGB ratio.
// R20/R21 post-mortem: the occupancy lever is falsified twice (R20 spill
// voided; R21 no-spill ran SLOWER at higher nominal occupancy -- likely
// 1 block/CU residency with 65.5KB LDS + two sequential block rounds).
// Standing model: VALU/trans-issue-bound (~53k cyc/SIMD: 32 exp2/chunk at
// trans rate) + unhidden MFMA dependency latency (~46k cyc pipe occupancy
// vs only ~7k issue); sum ~= measured 106k. The ONLY positive lever so far
// was R19's sched_group_barrier interleave (+2.5us) -- and it was mis-sized:
// requested 16x{3 MFMA,6 VALU}=48 MFMA/body, but the 2-chunk body has only
// 24 MFMAs, so the pattern died halfway and half the VALU stream stayed
// un-interleaved. R22 sizes it exactly: 12x{2 MFMA, 8 VALU} = 24:96.
__global__ __launch_bounds__(512, 4) void attn_kernel(
    const unsigned char* __restrict__ Qfr, const unsigned char* __restrict__ Kt,
    const unsigned short* __restrict__ Vt, float* __restrict__ out, int n)
{
  __shared__ float part[7][64][33];   // 59 KB padded (33: conflict-free)

  const int tid  = threadIdx.x;
  const int lane = tid & 63;
  const int jq   = tid >> 6;     // 0..7: key-range octant

  // wave phase-stagger: ~220 cyc per jq step, before any memory op.
  #pragma unroll 1
  for (int i = 0; i < jq; ++i) __builtin_amdgcn_s_sleep(3);

  const int bid  = blockIdx.x;
  const int h    = bid & 3;
  const int iblk = bid >> 2;
  const int l16  = lane & 15, quad = lane >> 4;
  const int i0   = iblk*64;
  const int ntq  = (n >> 3) >> 4;            // 16-key tiles per octant (64)
  const int nch  = ntq >> 1;                 // 32-key chunks per octant (32)
  const int tile0 = jq * ntq;

  // Q fragments: 4 i-tiles x 2 e-halves -- DENSE (one uint4 per i-tile)
  const unsigned char* qfh = Qfr + (size_t)h*((size_t)n<<6);
  longlong2 q0 = *(const longlong2*)(qfh + (size_t)((i0>>4)    )*1024 + lane*16);
  longlong2 q1 = *(const longlong2*)(qfh + (size_t)((i0>>4) + 1)*1024 + lane*16);
  longlong2 q2 = *(const longlong2*)(qfh + (size_t)((i0>>4) + 2)*1024 + lane*16);
  longlong2 q3 = *(const longlong2*)(qfh + (size_t)((i0>>4) + 3)*1024 + lane*16);
  const fp8x8 qf00 = (fp8x8)q0.x, qf01 = (fp8x8)q0.y;
  const fp8x8 qf10 = (fp8x8)q1.x, qf11 = (fp8x8)q1.y;
  const fp8x8 qf20 = (fp8x8)q2.x, qf21 = (fp8x8)q2.y;
  const fp8x8 qf30 = (fp8x8)q3.x, qf31 = (fp8x8)q3.y;

  const longlong2* ktl = (const longlong2*)(Kt + (size_t)h*((size_t)n<<6)) + (size_t)tile0*64 + lane;
  const uint4*     vtu = (const uint4*)(Vt + (size_t)h*((size_t)n<<4)) + (size_t)(tile0>>1)*64 + lane;

  const f32x4 z = {0.f,0.f,0.f,0.f};
  f32x4 o0 = z, o1 = z, o2 = z, o3 = z;
  f32x4 la0 = z, la1 = z, la2 = z, la3 = z;
  const bf16x8 vones = {(short)0x3F80, (short)0x3F80, (short)0x3F80, (short)0x3F80,
                        (short)0x3F80, (short)0x3F80, (short)0x3F80, (short)0x3F80};

  // prologue: chunk 0 in A regs, chunk 1 in B regs
  longlong2 ka0 = ktl[0],   ka1 = ktl[64];
  uint4     va  = vtu[0];
  longlong2 kb0 = ktl[128], kb1 = ktl[192];
  uint4     vb  = vtu[64];

// one i-tile granule: 4 QK MFMAs -> 8 exp2 -> 4 packs -> 2 PV MFMAs.
// Adjacent granules are fully independent (ILP for MFMA/VALU overlap).
#define ITILE(QA, QB, OO, LL)                                                 \
  {                                                                           \
    f32x4 s = __builtin_amdgcn_mfma_f32_16x16x32_fp8_fp8(a0, QA, z, 0,0,0);   \
    s = __builtin_amdgcn_mfma_f32_16x16x32_fp8_fp8(a1, QB, s, 0,0,0);         \
    f32x4 u = __builtin_amdgcn_mfma_f32_16x16x32_fp8_fp8(b0, QA, z, 0,0,0);   \
    u = __builtin_amdgcn_mfma_f32_16x16x32_fp8_fp8(b1, QB, u, 0,0,0);         \
    float e0 = __builtin_amdgcn_exp2f(s[0]);                                  \
    float e1 = __builtin_amdgcn_exp2f(s[1]);                                  \
    float e2 = __builtin_amdgcn_exp2f(s[2]);                                  \
    float e3 = __builtin_amdgcn_exp2f(s[3]);                                  \
    float f0 = __builtin_amdgcn_exp2f(u[0]);                                  \
    float f1 = __builtin_amdgcn_exp2f(u[1]);                                  \
    float f2 = __builtin_amdgcn_exp2f(u[2]);                                  \
    float f3 = __builtin_amdgcn_exp2f(u[3]);                                  \
    union { uint4 uu; bf16x8 v; } pq;                                         \
    pq.uu = make_uint4(pack2bf_t(e0,e1), pack2bf_t(e2,e3),                    \
                       pack2bf_t(f0,f1), pack2bf_t(f2,f3));                   \
    OO = __builtin_amdgcn_mfma_f32_16x16x32_bf16(pq.v, vfv,   OO, 0,0,0);     \
    LL = __builtin_amdgcn_mfma_f32_16x16x32_bf16(pq.v, vones, LL, 0,0,0);     \
  }

#define ATTN_CHUNK(KA, KB, VV)                                                \
  {                                                                           \
    const fp8x8 a0 = (fp8x8)KA.x, a1 = (fp8x8)KA.y;                           \
    const fp8x8 b0 = (fp8x8)KB.x, b1 = (fp8x8)KB.y;                           \
    union { uint4 uu; bf16x8 v; } vfu; vfu.uu = VV;                           \
    const bf16x8 vfv = vfu.v;                                                 \
    ITILE(qf00, qf01, o0, la0)                                                \
    ITILE(qf10, qf11, o1, la1)                                                \
    ITILE(qf20, qf21, o2, la2)                                                \
    ITILE(qf30, qf31, o3, la3)                                                \
  }

  // main loop, unrolled x2: process chunk c from A regs then reload A with
  // chunk c+2; same for B with c+1/c+3. No register moves.
  for (int c = 0; c < nch - 2; c += 2){
    ATTN_CHUNK(ka0, ka1, va)
    ka0 = ktl[256]; ka1 = ktl[320]; va = vtu[128];
    ATTN_CHUNK(kb0, kb1, vb)
    kb0 = ktl[384]; kb1 = ktl[448]; vb = vtu[192];
    ktl += 256; vtu += 128;
    // pipeline directive, sized EXACTLY to the 2-chunk body (24 MFMA, ~96
    // VALU/trans): 12 x {2 MFMA, 8 VALU}. Forces every exp2/pack stretch to
    // thread between MFMA pairs so MFMA dep-latency hides under VALU issue.
    #pragma unroll
    for (int g = 0; g < 12; ++g){
      __builtin_amdgcn_sched_group_barrier(0x008, 2, 0);  // 2 MFMA
      __builtin_amdgcn_sched_group_barrier(0x002, 8, 0);  // 8 VALU
    }
  }
  // tail: last two chunks, no prefetch
  ATTN_CHUNK(ka0, ka1, va)
  ATTN_CHUNK(kb0, kb1, vb)
#undef ATTN_CHUNK
#undef ITILE

  if (jq > 0){
    float* p = &part[jq-1][lane][0];
    p[ 0]=o0[0];  p[ 1]=o0[1];  p[ 2]=o0[2];  p[ 3]=o0[3];
    p[ 4]=o1[0];  p[ 5]=o1[1];  p[ 6]=o1[2];  p[ 7]=o1[3];
    p[ 8]=o2[0];  p[ 9]=o2[1];  p[10]=o2[2];  p[11]=o2[3];
    p[12]=o3[0];  p[13]=o3[1];  p[14]=o3[2];  p[15]=o3[3];
    p[16]=la0[0]; p[17]=la0[1]; p[18]=la0[2]; p[19]=la0[3];
    p[20]=la1[0]; p[21]=la1[1]; p[22]=la1[2]; p[23]=la1[3];
    p[24]=la2[0]; p[25]=la2[1]; p[26]=la2[2]; p[27]=la2[3];
    p[28]=la3[0]; p[29]=la3[1]; p[30]=la3[2]; p[31]=la3[3];
  }
  __syncthreads();

  if (jq == 0){
    #pragma unroll
    for (int q = 0; q < 7; ++q){
      const float* r = &part[q][lane][0];
      o0[0] +=r[0];  o0[1] +=r[1];  o0[2] +=r[2];  o0[3] +=r[3];
      o1[0] +=r[4];  o1[1] +=r[5];  o1[2] +=r[6];  o1[3] +=r[7];
      o2[0] +=r[8];  o2[1] +=r[9];  o2[2] +=r[10]; o2[3] +=r[11];
      o3[0] +=r[12]; o3[1] +=r[13]; o3[2] +=r[14]; o3[3] +=r[15];
      la0[0]+=r[16]; la0[1]+=r[17]; la0[2]+=r[18]; la0[3]+=r[19];
      la1[0]+=r[20]; la1[1]+=r[21]; la1[2]+=r[22]; la1[3]+=r[23];
      la2[0]+=r[24]; la2[1]+=r[25]; la2[2]+=r[26]; la2[3]+=r[27];
      la3[0]+=r[28]; la3[1]+=r[29]; la3[2]+=r[30]; la3[3]+=r[31];
    }
    #pragma unroll
    for (int reg = 0; reg < 4; ++reg){
      int i = quad*4 + reg;
      out[(size_t)(i0 +      i)*64 + h*16 + l16] = o0[reg] / la0[reg];
      out[(size_t)(i0 + 16 + i)*64 + h*16 + l16] = o1[reg] / la1[reg];
      out[(size_t)(i0 + 32 + i)*64 + h*16 + l16] = o2[reg] / la2[reg];
      out[(size_t)(i0 + 48 + i)*64 + h*16 + l16] = o3[reg] / la3[reg];
    }
  }
}

extern "C" void kernel_launch(void* const* d_in, const int* in_sizes, int n_in,
                              void* d_out, int out_size, void* d_ws, size_t ws_size,
                              hipStream_t stream) {
  const float* x  = (const float*)d_in[0];
  const float* Wq = (const float*)d_in[1];
  const float* bq = (const float*)d_in[2];
  const float* Wk = (const float*)d_in[3];
  const float* bk = (const float*)d_in[4];
  const float* Wv = (const float*)d_in[5];
  const float* bv = (const float*)d_in[6];
  float* out = (float*)d_out;

  const int n = in_sizes[0] / 64;   // 8192

  unsigned char* Qfr  = (unsigned char*)d_ws;                       // NH*n*64 B frag tiles (Q)
  unsigned char* Kt   = Qfr + (size_t)NH*n*64;                      // NH*n*64 B frag tiles (K)
  unsigned short* Vt  = (unsigned short*)(Kt + (size_t)NH*n*64);    // NH*n*16 u16 frag tiles (chunk-interleaved)
  unsigned short* WF  = Vt + (size_t)NH*n*16;                       // NH*18*64*8 u16 frags
  float* bias_s       = (float*)(WF + (size_t)NH*18*64*8);          // NH*128 f32

  wprep_kernel<<<NH, 256, 0, stream>>>(Wq, bq, Wk, bk, Wv, WF, bias_s, n);
  proj_kernel<<<dim3(n/64, NH), 256, 0, stream>>>(x, bv, WF, bias_s, Qfr, Kt, Vt, n);
  attn_kernel<<<dim3((n/64)*NH), 512, 0, stream>>>(Qfr, Kt, Vt, out, n);
}